// Round 1
// baseline (63.789 us; speedup 1.0000x reference)
//
#include <hip/hip_runtime.h>
#include <math.h>

#define NACC 24

__global__ void init_ws(double* ws) {
    int i = threadIdx.x;
    if (i < NACC) ws[i] = 0.0;
}

__device__ __forceinline__ void process_elem(double* acc, float dpv, float spv, float dv, float sv) {
    acc[0] += (dpv < spv) ? 1.0 : 0.0;
    acc[1] += (double)dv;  acc[2] += (double)dv * (double)dv;
    acc[3] += (double)dpv; acc[4] += (double)dpv * (double)dpv;
    acc[5] += (double)sv;  acc[6] += (double)sv * (double)sv;
    acc[7] += (double)spv; acc[8] += (double)spv * (double)spv;
    float smd = 2.0f * fabsf(dpv - dv) / (fabsf(dpv) + fabsf(dv));
    float sms = 2.0f * fabsf(spv - sv) / (fabsf(spv) + fabsf(sv));
    // mask precedence: & binds tighter than | in the reference
    bool m0 = (sv < 120.0f) && (dv < 80.0f);
    bool m1 = (sv >= 120.0f) && (sv < 130.0f) && (dv < 80.0f);
    bool m2 = ((sv >= 130.0f) && (sv < 140.0f)) || ((dv >= 80.0f) && (dv < 90.0f));
    bool m3 = (sv >= 140.0f) || (dv >= 90.0f);
    bool m4 = (sv > 180.0f) || (dv > 120.0f);
    acc[9]  += m0 ? 1.0 : 0.0;  acc[10] += m0 ? (double)smd : 0.0;  acc[11] += m0 ? (double)sms : 0.0;
    acc[12] += m1 ? 1.0 : 0.0;  acc[13] += m1 ? (double)smd : 0.0;  acc[14] += m1 ? (double)sms : 0.0;
    acc[15] += m2 ? 1.0 : 0.0;  acc[16] += m2 ? (double)smd : 0.0;  acc[17] += m2 ? (double)sms : 0.0;
    acc[18] += m3 ? 1.0 : 0.0;  acc[19] += m3 ? (double)smd : 0.0;  acc[20] += m3 ? (double)sms : 0.0;
    acc[21] += m4 ? 1.0 : 0.0;  acc[22] += m4 ? (double)smd : 0.0;  acc[23] += m4 ? (double)sms : 0.0;
}

__global__ __launch_bounds__(256) void amp_reduce(
    const float* __restrict__ dp, const float* __restrict__ sp,
    const float* __restrict__ d,  const float* __restrict__ s,
    double* __restrict__ ws, int n)
{
    double acc[NACC];
    #pragma unroll
    for (int k = 0; k < NACC; ++k) acc[k] = 0.0;

    const int tid = blockIdx.x * blockDim.x + threadIdx.x;
    const int stride = gridDim.x * blockDim.x;
    const int n4 = n >> 2;

    const float4* dp4 = (const float4*)dp;
    const float4* sp4 = (const float4*)sp;
    const float4* d4  = (const float4*)d;
    const float4* s4  = (const float4*)s;

    for (int i = tid; i < n4; i += stride) {
        float4 vdp = dp4[i];
        float4 vsp = sp4[i];
        float4 vd  = d4[i];
        float4 vs  = s4[i];
        process_elem(acc, vdp.x, vsp.x, vd.x, vs.x);
        process_elem(acc, vdp.y, vsp.y, vd.y, vs.y);
        process_elem(acc, vdp.z, vsp.z, vd.z, vs.z);
        process_elem(acc, vdp.w, vsp.w, vd.w, vs.w);
    }
    // scalar tail (n not divisible by 4)
    for (int i = (n4 << 2) + tid; i < n; i += stride) {
        process_elem(acc, dp[i], sp[i], d[i], s[i]);
    }

    // block reduction: wave shuffle -> LDS -> one atomic per value
    __shared__ double part[4][NACC];
    const int lane = threadIdx.x & 63;
    const int wave = threadIdx.x >> 6;
    #pragma unroll
    for (int k = 0; k < NACC; ++k) {
        double v = acc[k];
        #pragma unroll
        for (int off = 32; off > 0; off >>= 1)
            v += __shfl_down(v, off, 64);
        if (lane == 0) part[wave][k] = v;
    }
    __syncthreads();
    if (threadIdx.x < NACC) {
        double v = part[0][threadIdx.x] + part[1][threadIdx.x]
                 + part[2][threadIdx.x] + part[3][threadIdx.x];
        atomicAdd(&ws[threadIdx.x], v);
    }
}

__global__ void finalize_kernel(const double* __restrict__ ws, float* __restrict__ out, int n) {
    if (threadIdx.x != 0 || blockIdx.x != 0) return;
    const double nf = (double)n;
    const double lt = ws[0];
    const double sum_d  = ws[1], sum_d2  = ws[2];
    const double sum_dp = ws[3], sum_dp2 = ws[4];
    const double sum_s  = ws[5], sum_s2  = ws[6];
    const double sum_sp = ws[7], sum_sp2 = ws[8];

    double scale_cost = 1.0 - lt / nf;

    double d_rst = 0.0, s_rst = 0.0, rst_d = 0.0, rst_s = 0.0;
    int cnt = 0;
    #pragma unroll
    for (int i = 0; i < 5; ++i) {
        double c   = ws[9 + 3 * i];
        double sdi = ws[10 + 3 * i];
        double ssi = ws[11 + 3 * i];
        double safe = fmax(c, 1.0);
        double w = sqrt(log(nf / safe));
        double sum_di = w * sdi;
        double sum_si = w * ssi;
        bool has = c > 0.0;
        double nd = (d_rst + sum_di) / safe;
        double ns = (s_rst + sum_si) / safe;
        if (has) {
            d_rst = nd; s_rst = ns;
            rst_d += nd; rst_s += ns;
            cnt++;
        }
    }
    double denom = (cnt == 0) ? 5.0 : (double)cnt;
    rst_d /= denom;
    rst_s /= denom;

    double mean_d  = sum_d / nf,  mean_dp = sum_dp / nf;
    double mean_s  = sum_s / nf,  mean_sp = sum_sp / nf;
    double var_d  = (sum_d2  - nf * mean_d  * mean_d)  / (nf - 1.0);
    double var_dp = (sum_dp2 - nf * mean_dp * mean_dp) / (nf - 1.0);
    double var_s  = (sum_s2  - nf * mean_s  * mean_s)  / (nf - 1.0);
    double var_sp = (sum_sp2 - nf * mean_sp * mean_sp) / (nf - 1.0);

    double dbp_mean_cost = fabs(mean_d - mean_dp) / mean_d;
    double sbp_mean_cost = fabs(mean_s - mean_sp) / mean_s;
    double dbp_var_cost  = fabs(var_d - var_dp) / var_d;
    double sbp_var_cost  = fabs(var_s - var_sp) / var_s;

    out[0] = (float)(rst_d + dbp_mean_cost + dbp_var_cost);
    out[1] = (float)(rst_s + sbp_mean_cost + sbp_var_cost);
    out[2] = (float)scale_cost;
}

extern "C" void kernel_launch(void* const* d_in, const int* in_sizes, int n_in,
                              void* d_out, int out_size, void* d_ws, size_t ws_size,
                              hipStream_t stream) {
    const float* dp = (const float*)d_in[0];   // dbp_pred
    const float* sp = (const float*)d_in[1];   // sbp_pred
    // d_in[2] = mbp_pred (unused), d_in[5] = m (unused)
    const float* d  = (const float*)d_in[3];
    const float* s  = (const float*)d_in[4];
    const int n = in_sizes[0];

    double* ws = (double*)d_ws;
    float* out = (float*)d_out;

    hipLaunchKernelGGL(init_ws, dim3(1), dim3(32), 0, stream, ws);

    int n4 = n >> 2;
    int blocks = (n4 + 255) / 256;
    if (blocks > 2048) blocks = 2048;
    if (blocks < 1) blocks = 1;
    hipLaunchKernelGGL(amp_reduce, dim3(blocks), dim3(256), 0, stream,
                       dp, sp, d, s, ws, n);

    hipLaunchKernelGGL(finalize_kernel, dim3(1), dim3(1), 0, stream, ws, out, n);
}

// Round 2
// 62.893 us; speedup vs baseline: 1.0143x; 1.0143x over previous
//
#include <hip/hip_runtime.h>
#include <math.h>

#define NACC 24
#define GRID1 1024

// acc layout:
//  0: lt count          (dbp_pred < sbp_pred)
//  1: sum_d   2: sum_d2   3: sum_dp  4: sum_dp2
//  5: sum_s   6: sum_s2   7: sum_sp  8: sum_sp2
//  9,12,15,18,21: mask counts
// 10,13,16,19,22: mask . smape_d
// 11,14,17,20,23: mask . smape_s

__device__ __forceinline__ void process_elem(double* acc, int* cnt,
                                             float dpv, float spv, float dv, float sv) {
    cnt[0] += (dpv < spv) ? 1 : 0;
    acc[0] += (double)dv;  acc[1] += (double)dv * (double)dv;
    acc[2] += (double)dpv; acc[3] += (double)dpv * (double)dpv;
    acc[4] += (double)sv;  acc[5] += (double)sv * (double)sv;
    acc[6] += (double)spv; acc[7] += (double)spv * (double)spv;
    float smd = 2.0f * fabsf(dpv - dv) / (fabsf(dpv) + fabsf(dv));
    float sms = 2.0f * fabsf(spv - sv) / (fabsf(spv) + fabsf(sv));
    // mask precedence: & binds tighter than | in the reference
    bool m0 = (sv < 120.0f) && (dv < 80.0f);
    bool m1 = (sv >= 120.0f) && (sv < 130.0f) && (dv < 80.0f);
    bool m2 = ((sv >= 130.0f) && (sv < 140.0f)) || ((dv >= 80.0f) && (dv < 90.0f));
    bool m3 = (sv >= 140.0f) || (dv >= 90.0f);
    bool m4 = (sv > 180.0f) || (dv > 120.0f);
    cnt[1] += m0 ? 1 : 0;  acc[8]  += m0 ? (double)smd : 0.0;  acc[9]  += m0 ? (double)sms : 0.0;
    cnt[2] += m1 ? 1 : 0;  acc[10] += m1 ? (double)smd : 0.0;  acc[11] += m1 ? (double)sms : 0.0;
    cnt[3] += m2 ? 1 : 0;  acc[12] += m2 ? (double)smd : 0.0;  acc[13] += m2 ? (double)sms : 0.0;
    cnt[4] += m3 ? 1 : 0;  acc[14] += m3 ? (double)smd : 0.0;  acc[15] += m3 ? (double)sms : 0.0;
    cnt[5] += m4 ? 1 : 0;  acc[16] += m4 ? (double)smd : 0.0;  acc[17] += m4 ? (double)sms : 0.0;
}

__global__ __launch_bounds__(256) void amp_reduce(
    const float* __restrict__ dp, const float* __restrict__ sp,
    const float* __restrict__ d,  const float* __restrict__ s,
    double* __restrict__ partial, int n)
{
    double accD[18];
    int    accI[6];
    #pragma unroll
    for (int k = 0; k < 18; ++k) accD[k] = 0.0;
    #pragma unroll
    for (int k = 0; k < 6; ++k) accI[k] = 0;

    const int tid = blockIdx.x * blockDim.x + threadIdx.x;
    const int stride = gridDim.x * blockDim.x;
    const int n4 = n >> 2;

    const float4* dp4 = (const float4*)dp;
    const float4* sp4 = (const float4*)sp;
    const float4* d4  = (const float4*)d;
    const float4* s4  = (const float4*)s;

    for (int i = tid; i < n4; i += stride) {
        float4 vdp = dp4[i];
        float4 vsp = sp4[i];
        float4 vd  = d4[i];
        float4 vs  = s4[i];
        process_elem(accD, accI, vdp.x, vsp.x, vd.x, vs.x);
        process_elem(accD, accI, vdp.y, vsp.y, vd.y, vs.y);
        process_elem(accD, accI, vdp.z, vsp.z, vd.z, vs.z);
        process_elem(accD, accI, vdp.w, vsp.w, vd.w, vs.w);
    }
    for (int i = (n4 << 2) + tid; i < n; i += stride) {
        process_elem(accD, accI, dp[i], sp[i], d[i], s[i]);
    }

    // assemble the canonical 24-vector (counts -> double)
    double acc[NACC];
    acc[0] = (double)accI[0];
    #pragma unroll
    for (int k = 0; k < 8; ++k) acc[1 + k] = accD[k];
    #pragma unroll
    for (int g = 0; g < 5; ++g) {
        acc[9 + 3 * g]  = (double)accI[1 + g];
        acc[10 + 3 * g] = accD[8 + 2 * g];
        acc[11 + 3 * g] = accD[9 + 2 * g];
    }

    // block reduction: wave shuffle -> LDS -> per-block slot (NO atomics)
    __shared__ double part[4][NACC];
    const int lane = threadIdx.x & 63;
    const int wave = threadIdx.x >> 6;
    #pragma unroll
    for (int k = 0; k < NACC; ++k) {
        double v = acc[k];
        #pragma unroll
        for (int off = 32; off > 0; off >>= 1)
            v += __shfl_down(v, off, 64);
        if (lane == 0) part[wave][k] = v;
    }
    __syncthreads();
    if (threadIdx.x < NACC) {
        double v = part[0][threadIdx.x] + part[1][threadIdx.x]
                 + part[2][threadIdx.x] + part[3][threadIdx.x];
        // transposed layout: column k contiguous over blocks -> coalesced stage-2 reads
        partial[threadIdx.x * GRID1 + blockIdx.x] = v;
    }
}

__global__ __launch_bounds__(256) void amp_final(
    const double* __restrict__ partial, float* __restrict__ out, int n)
{
    __shared__ double tot[NACC];
    const int lane = threadIdx.x & 63;
    const int wave = threadIdx.x >> 6;

    // each wave reduces 6 of the 24 columns (GRID1 entries each, coalesced)
    for (int k = wave; k < NACC; k += 4) {
        double v = 0.0;
        for (int r = lane; r < GRID1; r += 64)
            v += partial[k * GRID1 + r];
        #pragma unroll
        for (int off = 32; off > 0; off >>= 1)
            v += __shfl_down(v, off, 64);
        if (lane == 0) tot[k] = v;
    }
    __syncthreads();

    if (threadIdx.x == 0) {
        const double nf = (double)n;
        const double lt = tot[0];
        const double sum_d  = tot[1], sum_d2  = tot[2];
        const double sum_dp = tot[3], sum_dp2 = tot[4];
        const double sum_s  = tot[5], sum_s2  = tot[6];
        const double sum_sp = tot[7], sum_sp2 = tot[8];

        double scale_cost = 1.0 - lt / nf;

        double d_rst = 0.0, s_rst = 0.0, rst_d = 0.0, rst_s = 0.0;
        int cnt = 0;
        #pragma unroll
        for (int i = 0; i < 5; ++i) {
            double c   = tot[9 + 3 * i];
            double sdi = tot[10 + 3 * i];
            double ssi = tot[11 + 3 * i];
            double safe = fmax(c, 1.0);
            double w = sqrt(log(nf / safe));
            double sum_di = w * sdi;
            double sum_si = w * ssi;
            bool has = c > 0.0;
            double nd = (d_rst + sum_di) / safe;
            double ns = (s_rst + sum_si) / safe;
            if (has) {
                d_rst = nd; s_rst = ns;
                rst_d += nd; rst_s += ns;
                cnt++;
            }
        }
        double denom = (cnt == 0) ? 5.0 : (double)cnt;
        rst_d /= denom;
        rst_s /= denom;

        double mean_d  = sum_d / nf,  mean_dp = sum_dp / nf;
        double mean_s  = sum_s / nf,  mean_sp = sum_sp / nf;
        double var_d  = (sum_d2  - nf * mean_d  * mean_d)  / (nf - 1.0);
        double var_dp = (sum_dp2 - nf * mean_dp * mean_dp) / (nf - 1.0);
        double var_s  = (sum_s2  - nf * mean_s  * mean_s)  / (nf - 1.0);
        double var_sp = (sum_sp2 - nf * mean_sp * mean_sp) / (nf - 1.0);

        double dbp_mean_cost = fabs(mean_d - mean_dp) / mean_d;
        double sbp_mean_cost = fabs(mean_s - mean_sp) / mean_s;
        double dbp_var_cost  = fabs(var_d - var_dp) / var_d;
        double sbp_var_cost  = fabs(var_s - var_sp) / var_s;

        out[0] = (float)(rst_d + dbp_mean_cost + dbp_var_cost);
        out[1] = (float)(rst_s + sbp_mean_cost + sbp_var_cost);
        out[2] = (float)scale_cost;
    }
}

extern "C" void kernel_launch(void* const* d_in, const int* in_sizes, int n_in,
                              void* d_out, int out_size, void* d_ws, size_t ws_size,
                              hipStream_t stream) {
    const float* dp = (const float*)d_in[0];   // dbp_pred
    const float* sp = (const float*)d_in[1];   // sbp_pred
    // d_in[2] = mbp_pred (unused), d_in[5] = m (unused)
    const float* d  = (const float*)d_in[3];
    const float* s  = (const float*)d_in[4];
    const int n = in_sizes[0];

    double* partial = (double*)d_ws;           // NACC * GRID1 doubles = 192 KiB
    float* out = (float*)d_out;

    hipLaunchKernelGGL(amp_reduce, dim3(GRID1), dim3(256), 0, stream,
                       dp, sp, d, s, partial, n);
    hipLaunchKernelGGL(amp_final, dim3(1), dim3(256), 0, stream,
                       partial, out, n);
}

// Round 3
// 35.189 us; speedup vs baseline: 1.8128x; 1.7873x over previous
//
#include <hip/hip_runtime.h>
#include <math.h>

#define NACC 24
#define GRID1 1024

// acc layout:
//  0: lt count          (dbp_pred < sbp_pred)
//  1: sum_d   2: sum_d2   3: sum_dp  4: sum_dp2
//  5: sum_s   6: sum_s2   7: sum_sp  8: sum_sp2
//  9,12,15,18,21: mask counts
// 10,13,16,19,22: mask . smape_d
// 11,14,17,20,23: mask . smape_s

__device__ __forceinline__ void process_elem(double* acc, int* cnt,
                                             float dpv, float spv, float dv, float sv) {
    cnt[0] += (dpv < spv) ? 1 : 0;
    acc[0] += (double)dv;  acc[1] += (double)dv * (double)dv;
    acc[2] += (double)dpv; acc[3] += (double)dpv * (double)dpv;
    acc[4] += (double)sv;  acc[5] += (double)sv * (double)sv;
    acc[6] += (double)spv; acc[7] += (double)spv * (double)spv;
    float smd = 2.0f * fabsf(dpv - dv) / (fabsf(dpv) + fabsf(dv));
    float sms = 2.0f * fabsf(spv - sv) / (fabsf(spv) + fabsf(sv));
    // mask precedence: & binds tighter than | in the reference
    bool m0 = (sv < 120.0f) && (dv < 80.0f);
    bool m1 = (sv >= 120.0f) && (sv < 130.0f) && (dv < 80.0f);
    bool m2 = ((sv >= 130.0f) && (sv < 140.0f)) || ((dv >= 80.0f) && (dv < 90.0f));
    bool m3 = (sv >= 140.0f) || (dv >= 90.0f);
    bool m4 = (sv > 180.0f) || (dv > 120.0f);
    cnt[1] += m0 ? 1 : 0;  acc[8]  += m0 ? (double)smd : 0.0;  acc[9]  += m0 ? (double)sms : 0.0;
    cnt[2] += m1 ? 1 : 0;  acc[10] += m1 ? (double)smd : 0.0;  acc[11] += m1 ? (double)sms : 0.0;
    cnt[3] += m2 ? 1 : 0;  acc[12] += m2 ? (double)smd : 0.0;  acc[13] += m2 ? (double)sms : 0.0;
    cnt[4] += m3 ? 1 : 0;  acc[14] += m3 ? (double)smd : 0.0;  acc[15] += m3 ? (double)sms : 0.0;
    cnt[5] += m4 ? 1 : 0;  acc[16] += m4 ? (double)smd : 0.0;  acc[17] += m4 ? (double)sms : 0.0;
}

__global__ __launch_bounds__(256) void amp_reduce(
    const float* __restrict__ dp, const float* __restrict__ sp,
    const float* __restrict__ d,  const float* __restrict__ s,
    double* __restrict__ partial, int n)
{
    double accD[18];
    int    accI[6];
    #pragma unroll
    for (int k = 0; k < 18; ++k) accD[k] = 0.0;
    #pragma unroll
    for (int k = 0; k < 6; ++k) accI[k] = 0;

    const int tid = blockIdx.x * blockDim.x + threadIdx.x;
    const int stride = gridDim.x * blockDim.x;
    const int n4 = n >> 2;

    const float4* dp4 = (const float4*)dp;
    const float4* sp4 = (const float4*)sp;
    const float4* d4  = (const float4*)d;
    const float4* s4  = (const float4*)s;

    for (int i = tid; i < n4; i += stride) {
        float4 vdp = dp4[i];
        float4 vsp = sp4[i];
        float4 vd  = d4[i];
        float4 vs  = s4[i];
        process_elem(accD, accI, vdp.x, vsp.x, vd.x, vs.x);
        process_elem(accD, accI, vdp.y, vsp.y, vd.y, vs.y);
        process_elem(accD, accI, vdp.z, vsp.z, vd.z, vs.z);
        process_elem(accD, accI, vdp.w, vsp.w, vd.w, vs.w);
    }
    for (int i = (n4 << 2) + tid; i < n; i += stride) {
        process_elem(accD, accI, dp[i], sp[i], d[i], s[i]);
    }

    // assemble the canonical 24-vector (counts -> double)
    double acc[NACC];
    acc[0] = (double)accI[0];
    #pragma unroll
    for (int k = 0; k < 8; ++k) acc[1 + k] = accD[k];
    #pragma unroll
    for (int g = 0; g < 5; ++g) {
        acc[9 + 3 * g]  = (double)accI[1 + g];
        acc[10 + 3 * g] = accD[8 + 2 * g];
        acc[11 + 3 * g] = accD[9 + 2 * g];
    }

    // block reduction: wave shuffle -> LDS -> per-block slot (NO atomics)
    __shared__ double part[4][NACC];
    const int lane = threadIdx.x & 63;
    const int wave = threadIdx.x >> 6;
    #pragma unroll
    for (int k = 0; k < NACC; ++k) {
        double v = acc[k];
        #pragma unroll
        for (int off = 32; off > 0; off >>= 1)
            v += __shfl_down(v, off, 64);
        if (lane == 0) part[wave][k] = v;
    }
    __syncthreads();
    if (threadIdx.x < NACC) {
        double v = part[0][threadIdx.x] + part[1][threadIdx.x]
                 + part[2][threadIdx.x] + part[3][threadIdx.x];
        // transposed layout: column k contiguous over blocks -> coalesced stage-2 reads
        partial[threadIdx.x * GRID1 + blockIdx.x] = v;
    }
}

// 1024 threads = 16 waves. Wave w reduces columns {w, w+16}; full unroll with
// 4 independent accumulators so the 16 loads per column pipeline (1 latency
// exposure per column instead of 16 dependent loads).
__global__ __launch_bounds__(1024) void amp_final(
    const double* __restrict__ partial, float* __restrict__ out, int n)
{
    __shared__ double tot[NACC];
    const int lane = threadIdx.x & 63;
    const int wave = threadIdx.x >> 6;

    for (int k = wave; k < NACC; k += 16) {
        const double* col = partial + k * GRID1 + lane;
        double v0 = 0.0, v1 = 0.0, v2 = 0.0, v3 = 0.0;
        #pragma unroll
        for (int r = 0; r < GRID1 / 64; r += 4) {
            v0 += col[(r + 0) * 64];
            v1 += col[(r + 1) * 64];
            v2 += col[(r + 2) * 64];
            v3 += col[(r + 3) * 64];
        }
        double v = (v0 + v1) + (v2 + v3);
        #pragma unroll
        for (int off = 32; off > 0; off >>= 1)
            v += __shfl_down(v, off, 64);
        if (lane == 0) tot[k] = v;
    }
    __syncthreads();

    if (threadIdx.x == 0) {
        const double nf = (double)n;
        const double lt = tot[0];
        const double sum_d  = tot[1], sum_d2  = tot[2];
        const double sum_dp = tot[3], sum_dp2 = tot[4];
        const double sum_s  = tot[5], sum_s2  = tot[6];
        const double sum_sp = tot[7], sum_sp2 = tot[8];

        double scale_cost = 1.0 - lt / nf;

        double d_rst = 0.0, s_rst = 0.0, rst_d = 0.0, rst_s = 0.0;
        int cnt = 0;
        #pragma unroll
        for (int i = 0; i < 5; ++i) {
            double c   = tot[9 + 3 * i];
            double sdi = tot[10 + 3 * i];
            double ssi = tot[11 + 3 * i];
            double safe = fmax(c, 1.0);
            double w = sqrt(log(nf / safe));
            double sum_di = w * sdi;
            double sum_si = w * ssi;
            bool has = c > 0.0;
            double nd = (d_rst + sum_di) / safe;
            double ns = (s_rst + sum_si) / safe;
            if (has) {
                d_rst = nd; s_rst = ns;
                rst_d += nd; rst_s += ns;
                cnt++;
            }
        }
        double denom = (cnt == 0) ? 5.0 : (double)cnt;
        rst_d /= denom;
        rst_s /= denom;

        double mean_d  = sum_d / nf,  mean_dp = sum_dp / nf;
        double mean_s  = sum_s / nf,  mean_sp = sum_sp / nf;
        double var_d  = (sum_d2  - nf * mean_d  * mean_d)  / (nf - 1.0);
        double var_dp = (sum_dp2 - nf * mean_dp * mean_dp) / (nf - 1.0);
        double var_s  = (sum_s2  - nf * mean_s  * mean_s)  / (nf - 1.0);
        double var_sp = (sum_sp2 - nf * mean_sp * mean_sp) / (nf - 1.0);

        double dbp_mean_cost = fabs(mean_d - mean_dp) / mean_d;
        double sbp_mean_cost = fabs(mean_s - mean_sp) / mean_s;
        double dbp_var_cost  = fabs(var_d - var_dp) / var_d;
        double sbp_var_cost  = fabs(var_s - var_sp) / var_s;

        out[0] = (float)(rst_d + dbp_mean_cost + dbp_var_cost);
        out[1] = (float)(rst_s + sbp_mean_cost + sbp_var_cost);
        out[2] = (float)scale_cost;
    }
}

extern "C" void kernel_launch(void* const* d_in, const int* in_sizes, int n_in,
                              void* d_out, int out_size, void* d_ws, size_t ws_size,
                              hipStream_t stream) {
    const float* dp = (const float*)d_in[0];   // dbp_pred
    const float* sp = (const float*)d_in[1];   // sbp_pred
    // d_in[2] = mbp_pred (unused), d_in[5] = m (unused)
    const float* d  = (const float*)d_in[3];
    const float* s  = (const float*)d_in[4];
    const int n = in_sizes[0];

    double* partial = (double*)d_ws;           // NACC * GRID1 doubles = 192 KiB
    float* out = (float*)d_out;

    hipLaunchKernelGGL(amp_reduce, dim3(GRID1), dim3(256), 0, stream,
                       dp, sp, d, s, partial, n);
    hipLaunchKernelGGL(amp_final, dim3(1), dim3(1024), 0, stream,
                       partial, out, n);
}